// Round 4
// baseline (528.805 us; speedup 1.0000x reference)
//
#include <hip/hip_runtime.h>
#include <hip/hip_bf16.h>

#define VOCAB 32000
#define EMBED 1024
#define SEQ 256
#define BATCH 8
#define ROWS (SEQ * BATCH) /* 2048 */

#define BM 256
#define BN 256
#define BK 64
#define NT (EMBED / BK) /* 16 K-tiles */

typedef short short8 __attribute__((ext_vector_type(8)));
typedef float f32x4 __attribute__((ext_vector_type(4)));

__device__ __forceinline__ unsigned short f2bf(float f) {
    __hip_bfloat16 h = __float2bfloat16(f);
    return *reinterpret_cast<unsigned short*>(&h);
}

#define GLOAD_LDS16(gsrc, ldst)                                                        \
    __builtin_amdgcn_global_load_lds((const __attribute__((address_space(1))) void*)(gsrc), \
                                     (__attribute__((address_space(3))) void*)(ldst), 16, 0, 0)

// ---------------- fused pre-pass: transpose (blocks 0..7999) + embed (blocks 8000..10047) ----------------
__global__ __launch_bounds__(256) void prep_k(const int* __restrict__ toks,
                                              const float* __restrict__ W1,
                                              const float* __restrict__ b1,
                                              const float* __restrict__ W2,
                                              unsigned short* __restrict__ h,
                                              unsigned short* __restrict__ W2t) {
    __shared__ float tile[64][65];
    int bid = blockIdx.x;
    int t = threadIdx.x;
    if (bid < 8000) {
        // W2 [1024][32000] f32 -> W2t [32000][1024] bf16
        int n0 = (bid % 500) * 64;
        int k0 = (bid / 500) * 64;
        int tx = t & 15, ty = t >> 4;
#pragma unroll
        for (int p = 0; p < 4; ++p) {
            int k = ty + p * 16;
            float4 v = *(const float4*)(W2 + (size_t)(k0 + k) * VOCAB + n0 + tx * 4);
            tile[k][tx * 4 + 0] = v.x; tile[k][tx * 4 + 1] = v.y;
            tile[k][tx * 4 + 2] = v.z; tile[k][tx * 4 + 3] = v.w;
        }
        __syncthreads();
        int kx = t & 15, ny = t >> 4;
#pragma unroll
        for (int p = 0; p < 4; ++p) {
            int n = ny + p * 16;
            int k = kx * 4;
            union { unsigned short u[4]; uint2 v; } o;
            o.u[0] = f2bf(tile[k + 0][n]); o.u[1] = f2bf(tile[k + 1][n]);
            o.u[2] = f2bf(tile[k + 2][n]); o.u[3] = f2bf(tile[k + 3][n]);
            *(uint2*)(W2t + (size_t)(n0 + n) * EMBED + k0 + k) = o.v;
        }
    } else {
        // h = relu(b1 + sum_j W1r[j][ctx_j]) -> bf16
        int r = bid - 8000;
        int s = r >> 3, b = r & 7;
        int t0 = (s >= 3) ? toks[(s - 3) * BATCH + b] : 0;
        int t1 = (s >= 2) ? toks[(s - 2) * BATCH + b] : 0;
        int t2 = (s >= 1) ? toks[(s - 1) * BATCH + b] : 0;
        int e = t * 4;
        float4 vb = *(const float4*)(b1 + e);
        float4 v0 = *(const float4*)(W1 + ((size_t)0 * VOCAB + t0) * EMBED + e);
        float4 v1 = *(const float4*)(W1 + ((size_t)1 * VOCAB + t1) * EMBED + e);
        float4 v2 = *(const float4*)(W1 + ((size_t)2 * VOCAB + t2) * EMBED + e);
        float x0 = fmaxf(vb.x + v0.x + v1.x + v2.x, 0.0f);
        float x1 = fmaxf(vb.y + v0.y + v1.y + v2.y, 0.0f);
        float x2 = fmaxf(vb.z + v0.z + v1.z + v2.z, 0.0f);
        float x3 = fmaxf(vb.w + v0.w + v1.w + v2.w, 0.0f);
        union { unsigned short u[4]; uint2 v; } o;
        o.u[0] = f2bf(x0); o.u[1] = f2bf(x1); o.u[2] = f2bf(x2); o.u[3] = f2bf(x3);
        *(uint2*)(h + (size_t)r * EMBED + e) = o.v;
    }
}

// ---------------- persistent 256x256 8-phase bf16 MFMA GEMM: 2 m-tiles per block ----------------
// LDS (dynamic 128 KiB): A [2 buf][256 rows][128 B]; B at +65536.
// Swizzle: phys_byte = row*128 + (colbyte ^ ((row&7)<<4)).
// XCD mapping: mg outer (wgid/125) -> each XCD serves ONE 1 MB A-slab (L2-resident);
// B stripes shared cross-XCD via L3. Epilogue stores are non-temporal (don't evict A).
// Boundary: wrap prefetches leave buf0.B=B(t0), buf1.B=B(t1); pre-stage BOTH A(t0) and
// A(t1) for the next m-slab BEFORE the epilogue stores (queue-cap 63 guarantees the 12
// pre-epi loads retire while the 128 stores issue), then run iteration 0 with no ph1-2
// staging and NO ph4 vmcnt -> first counted wait is 6+ phases past the stores.
__global__ __launch_bounds__(512, 2) void gemm8_k(const unsigned short* __restrict__ A,
                                                  const unsigned short* __restrict__ B,
                                                  const float* __restrict__ b2,
                                                  float* __restrict__ out) {
    extern __shared__ char lds[];
    char* Al = lds;
    char* Bl = lds + 65536;

    // bijective XCD swizzle for 500 blocks (m204): q=62, r=4
    int wg = blockIdx.x;
    int xcd = wg & 7, idx = wg >> 3;
    int wgid = (xcd < 4 ? xcd * 63 : 4 * 63 + (xcd - 4) * 62) + idx;
    int mg = wgid / 125;          // m-group OUTER: one A-slab per XCD (L2-resident)
    int ns = wgid % 125;          // n-stripe fast within XCD
    int n0 = ns * BN;
    int m0 = mg * 512;            // this block covers m0 and m0+256

    int tid = threadIdx.x;
    int w = tid >> 6, lane = tid & 63;
    int wm = w >> 2, wn = w & 3;                       // 2 x 4 wave grid
    int ksw = ((lane & 7) ^ ((lane >> 3) & 7)) * 8;    // staging inverse-swizzle (elements)

    f32x4 acc[8][4] = {};
    short8 af[2][2], bfr[4][2];

    // ---- staging: one 128x64 half-tile = 16 KB; each wave does 2 x 1KB chunks ----
    auto stage = [&](const unsigned short* __restrict__ g, int grow0, char* ldsbase, int t) {
#pragma unroll
        for (int j = 0; j < 2; ++j) {
            int c = j * 8 + w;
            int row = c * 8 + (lane >> 3);
            const unsigned short* src = g + (size_t)(grow0 + row) * EMBED + t * BK + ksw;
            GLOAD_LDS16(src, ldsbase + c * 1024);
        }
    };
    auto stA = [&](int buf, int hh, int t, int mbase) { stage(A, mbase + hh * 128, Al + buf * 32768 + hh * 16384, t); };
    auto stB = [&](int buf, int hh, int t) { stage(B, n0 + hh * 128, Bl + buf * 32768 + hh * 16384, t); };

    // ---- register loads (swizzled ds_read_b128) ----
    auto ldA = [&](int buf, int qq) {
#pragma unroll
        for (int i = 0; i < 2; ++i)
#pragma unroll
            for (int kk = 0; kk < 2; ++kk) {
                int row = wm * 128 + (qq * 2 + i) * 16 + (lane & 15);
                int cb = ((lane >> 4) * 16 + kk * 64) ^ ((lane & 7) << 4);
                af[i][kk] = *(const short8*)(Al + buf * 32768 + row * 128 + cb);
            }
    };
    auto ldB = [&](int buf) {
#pragma unroll
        for (int n = 0; n < 4; ++n)
#pragma unroll
            for (int kk = 0; kk < 2; ++kk) {
                int row = wn * 64 + n * 16 + (lane & 15);
                int cb = ((lane >> 4) * 16 + kk * 64) ^ ((lane & 7) << 4);
                bfr[n][kk] = *(const short8*)(Bl + buf * 32768 + row * 128 + cb);
            }
    };

#define MFMA_Q(q)                                                                             \
    __builtin_amdgcn_s_setprio(1);                                                            \
    _Pragma("unroll") for (int i = 0; i < 2; ++i)                                             \
        _Pragma("unroll") for (int n = 0; n < 4; ++n)                                         \
            _Pragma("unroll") for (int kk = 0; kk < 2; ++kk)                                  \
                acc[(q)*2 + i][n] = __builtin_amdgcn_mfma_f32_16x16x32_bf16(                  \
                    af[i][kk], bfr[n][kk], acc[(q)*2 + i][n], 0, 0, 0);                       \
    __builtin_amdgcn_s_setprio(0);

#define PH(ldbuf, q, DO_LDB, STAGE_STMT, WAITV)                                               \
    ldA(ldbuf, q);                                                                            \
    if (DO_LDB) ldB(ldbuf);                                                                   \
    STAGE_STMT;                                                                               \
    if (DO_LDB) asm volatile("s_waitcnt lgkmcnt(8)");                                         \
    if (WAITV) asm volatile("s_waitcnt vmcnt(4)");                                            \
    __builtin_amdgcn_s_barrier();                                                             \
    asm volatile("s_waitcnt lgkmcnt(0)");                                                     \
    MFMA_Q(q);                                                                                \
    __builtin_amdgcn_s_barrier();

    // 8-phase K-loop; wrap prefetches at it=7 restore prologue B-state for the next m-tile.
    // skipFirstA: tile t0 AND t1 A/B fully pre-staged -> it0 skips ph1-2 stages and ph4 vmcnt.
    auto kloop = [&](int mcur, bool skipFirstA) {
        for (int it = 0; it < NT / 2; ++it) {
            int t1 = (it * 2 + 1) & (NT - 1);
            int t2 = (it * 2 + 2) & (NT - 1);
            int t3 = (it * 2 + 3) & (NT - 1);
            if (it == 0 && skipFirstA) {
                PH(0, 0, true,  (void)0,             false)
                PH(0, 1, false, (void)0,             false)
                PH(0, 2, false, stB(0, 0, t2),       false)
                PH(0, 3, false, stB(0, 1, t2),       false)  // no vmcnt: t1 pre-landed
                PH(1, 0, true,  stA(0, 0, t2, mcur), false)
                PH(1, 1, false, stA(0, 1, t2, mcur), false)
                PH(1, 2, false, stB(1, 0, t3),       false)
                PH(1, 3, false, stB(1, 1, t3),       true)
            } else {
                PH(0, 0, true,  stA(1, 0, t1, mcur), false)
                PH(0, 1, false, stA(1, 1, t1, mcur), false)
                PH(0, 2, false, stB(0, 0, t2),       false)
                PH(0, 3, false, stB(0, 1, t2),       true)
                PH(1, 0, true,  stA(0, 0, t2, mcur), false)
                PH(1, 1, false, stA(0, 1, t2, mcur), false)
                PH(1, 2, false, stB(1, 0, t3),       false)
                PH(1, 3, false, stB(1, 1, t3),       true)
            }
        }
    };

    // ---- epilogue stores (non-temporal): C/D layout col=lane&15, row=(lane>>4)*4+q ----
    int colq = lane & 15;
    int rowq = (lane >> 4) * 4;
    auto epi = [&](int mbase) {
#pragma unroll
        for (int nf = 0; nf < 4; ++nf) {
            int col = n0 + wn * 64 + nf * 16 + colq;
            float bias = b2[col];
#pragma unroll
            for (int mf = 0; mf < 8; ++mf) {
                int row0 = mbase + wm * 128 + mf * 16 + rowq;
#pragma unroll
                for (int q = 0; q < 4; ++q)
                    __builtin_nontemporal_store(acc[mf][nf][q] + bias,
                                                &out[(size_t)(row0 + q) * VOCAB + col]);
            }
        }
    };

    // ---- prologue (m-tile 0): tile0 A+B -> buf0, B(tile1) -> buf1 ----
    stA(0, 0, 0, m0); stA(0, 1, 0, m0); stB(0, 0, 0); stB(0, 1, 0);
    stB(1, 0, 1); stB(1, 1, 1);
    asm volatile("s_waitcnt vmcnt(4)");
    __builtin_amdgcn_s_barrier();

    kloop(m0, false);

    // ---- boundary: buf0.B=B(t0), buf1.B=B(t1) from wrap prefetch. Pre-stage the new
    // m-slab's A for BOTH t0->buf0 and t1->buf1 (8 loads) before the 128 stores.
    int m1 = m0 + 256;
    stA(0, 0, 0, m1); stA(0, 1, 0, m1);
    stA(1, 0, 1, m1); stA(1, 1, 1, m1);
    epi(m0);
    asm volatile("s_waitcnt vmcnt(63)" ::: "memory");
    __builtin_amdgcn_s_barrier();

#pragma unroll
    for (int mf = 0; mf < 8; ++mf)
#pragma unroll
        for (int nf = 0; nf < 4; ++nf)
            acc[mf][nf] = f32x4{0.f, 0.f, 0.f, 0.f};

    kloop(m1, true);
    epi(m1);
#undef PH
#undef MFMA_Q
}

// ---------------- fallback 128^2 2-phase GEMM (if 128 KiB dyn LDS unavailable) ----------------
__global__ __launch_bounds__(256) void gemm_k(const unsigned short* __restrict__ h,
                                              const unsigned short* __restrict__ W2t,
                                              const float* __restrict__ b2,
                                              float* __restrict__ out) {
    __shared__ unsigned short Alds[128 * 64];
    __shared__ unsigned short Blds[128 * 64];
    int m0 = blockIdx.x * 128;
    int n0 = blockIdx.y * 128;
    int tid = threadIdx.x;
    int wave = tid >> 6, lane = tid & 63;
    int wr = (wave >> 1) * 64;
    int wc = (wave & 1) * 64;
    int lrow = lane & 15;
    int khalf = (lane >> 4) * 8;
    f32x4 acc[4][4] = {};
    for (int kt = 0; kt < EMBED; kt += 64) {
#pragma unroll
        for (int i = 0; i < 4; ++i) {
            int base = (wave * 4 + i) * 1024;
            int lin = base + lane * 16;
            int row = lin >> 7;
            int colu = (lin & 127) >> 1;
            GLOAD_LDS16(h + (size_t)(m0 + row) * EMBED + kt + colu, (char*)Alds + base);
            GLOAD_LDS16(W2t + (size_t)(n0 + row) * EMBED + kt + colu, (char*)Blds + base);
        }
        __syncthreads();
#pragma unroll
        for (int kc = 0; kc < 2; ++kc) {
            short8 af[4], bf[4];
#pragma unroll
            for (int m = 0; m < 4; ++m)
                af[m] = *(const short8*)(Alds + (wr + m * 16 + lrow) * 64 + kc * 32 + khalf);
#pragma unroll
            for (int n = 0; n < 4; ++n)
                bf[n] = *(const short8*)(Blds + (wc + n * 16 + lrow) * 64 + kc * 32 + khalf);
#pragma unroll
            for (int m = 0; m < 4; ++m)
#pragma unroll
                for (int n = 0; n < 4; ++n)
                    acc[m][n] = __builtin_amdgcn_mfma_f32_16x16x32_bf16(af[m], bf[n], acc[m][n], 0, 0, 0);
        }
        __syncthreads();
    }
    int colq = lane & 15;
    int rowq = (lane >> 4) * 4;
#pragma unroll
    for (int m = 0; m < 4; ++m)
#pragma unroll
        for (int n = 0; n < 4; ++n) {
            int col = n0 + wc + n * 16 + colq;
            float bias = b2[col];
#pragma unroll
            for (int q = 0; q < 4; ++q)
                out[(size_t)(m0 + wr + m * 16 + rowq + q) * VOCAB + col] = acc[m][n][q] + bias;
        }
}

// ---------------- fallback (ws too small): correct fp32 path ----------------
__global__ __launch_bounds__(256) void naive_k(const int* __restrict__ toks,
                                               const float* __restrict__ W1,
                                               const float* __restrict__ b1,
                                               const float* __restrict__ W2,
                                               const float* __restrict__ b2,
                                               float* __restrict__ out) {
    __shared__ float hs[8][1024];
    int r0 = blockIdx.x * 8;
    int e = threadIdx.x * 4;
    for (int rr = 0; rr < 8; ++rr) {
        int r = r0 + rr, s = r >> 3, b = r & 7;
        int t0 = (s >= 3) ? toks[(s - 3) * BATCH + b] : 0;
        int t1 = (s >= 2) ? toks[(s - 2) * BATCH + b] : 0;
        int t2 = (s >= 1) ? toks[(s - 1) * BATCH + b] : 0;
        float4 vb = *(const float4*)(b1 + e);
        float4 v0 = *(const float4*)(W1 + ((size_t)t0) * EMBED + e);
        float4 v1 = *(const float4*)(W1 + ((size_t)VOCAB + t1) * EMBED + e);
        float4 v2 = *(const float4*)(W1 + ((size_t)2 * VOCAB + t2) * EMBED + e);
        hs[rr][e + 0] = fmaxf(vb.x + v0.x + v1.x + v2.x, 0.0f);
        hs[rr][e + 1] = fmaxf(vb.y + v0.y + v1.y + v2.y, 0.0f);
        hs[rr][e + 2] = fmaxf(vb.z + v0.z + v1.z + v2.z, 0.0f);
        hs[rr][e + 3] = fmaxf(vb.w + v0.w + v1.w + v2.w, 0.0f);
    }
    __syncthreads();
    for (int v = threadIdx.x; v < VOCAB; v += 256) {
        float acc[8];
#pragma unroll
        for (int i = 0; i < 8; ++i) acc[i] = b2[v];
        for (int ee = 0; ee < EMBED; ++ee) {
            float wv = W2[(size_t)ee * VOCAB + v];
#pragma unroll
            for (int i = 0; i < 8; ++i) acc[i] += hs[i][ee] * wv;
        }
#pragma unroll
        for (int i = 0; i < 8; ++i) out[(size_t)(r0 + i) * VOCAB + v] = acc[i];
    }
}

extern "C" void kernel_launch(void* const* d_in, const int* in_sizes, int n_in,
                              void* d_out, int out_size, void* d_ws, size_t ws_size,
                              hipStream_t stream) {
    const int* toks = (const int*)d_in[0];
    const float* W1 = (const float*)d_in[1];
    const float* b1 = (const float*)d_in[2];
    const float* W2 = (const float*)d_in[3];
    const float* b2 = (const float*)d_in[4];
    float* out = (float*)d_out;

    const size_t h_bytes = (size_t)ROWS * EMBED * 2;
    const size_t w2t_bytes = (size_t)VOCAB * EMBED * 2;
    if (ws_size >= h_bytes + w2t_bytes) {
        unsigned short* h = (unsigned short*)d_ws;
        unsigned short* W2t = (unsigned short*)((char*)d_ws + h_bytes);
        prep_k<<<8000 + ROWS, 256, 0, stream>>>(toks, W1, b1, W2, h, W2t);
        hipError_t e = hipFuncSetAttribute(reinterpret_cast<const void*>(gemm8_k),
                                           hipFuncAttributeMaxDynamicSharedMemorySize, 131072);
        if (e == hipSuccess) {
            gemm8_k<<<(ROWS / 512) * (VOCAB / BN), 512, 131072, stream>>>(h, W2t, b2, out);
        } else {
            gemm_k<<<dim3(ROWS / 128, VOCAB / 128), 256, 0, stream>>>(h, W2t, b2, out);
        }
    } else {
        naive_k<<<ROWS / 8, 256, 0, stream>>>(toks, W1, b1, W2, b2, out);
    }
}

// Round 5
// 178.273 us; speedup vs baseline: 2.9663x; 2.9663x over previous
//
#include <hip/hip_runtime.h>
#include <hip/hip_bf16.h>

#define VOCAB 32000
#define EMBED 1024
#define SEQ 256
#define BATCH 8
#define ROWS (SEQ * BATCH) /* 2048 */

#define BM 256
#define BN 256
#define BK 64
#define NT (EMBED / BK) /* 16 K-tiles */

typedef short short8 __attribute__((ext_vector_type(8)));
typedef float f32x4 __attribute__((ext_vector_type(4)));

__device__ __forceinline__ unsigned short f2bf(float f) {
    __hip_bfloat16 h = __float2bfloat16(f);
    return *reinterpret_cast<unsigned short*>(&h);
}

#define GLOAD_LDS16(gsrc, ldst)                                                        \
    __builtin_amdgcn_global_load_lds((const __attribute__((address_space(1))) void*)(gsrc), \
                                     (__attribute__((address_space(3))) void*)(ldst), 16, 0, 0)

// ---------------- fused pre-pass: transpose (blocks 0..7999) + embed (blocks 8000..10047) ----------------
__global__ __launch_bounds__(256) void prep_k(const int* __restrict__ toks,
                                              const float* __restrict__ W1,
                                              const float* __restrict__ b1,
                                              const float* __restrict__ W2,
                                              unsigned short* __restrict__ h,
                                              unsigned short* __restrict__ W2t) {
    __shared__ float tile[64][65];
    int bid = blockIdx.x;
    int t = threadIdx.x;
    if (bid < 8000) {
        int n0 = (bid % 500) * 64;
        int k0 = (bid / 500) * 64;
        int tx = t & 15, ty = t >> 4;
#pragma unroll
        for (int p = 0; p < 4; ++p) {
            int k = ty + p * 16;
            float4 v = *(const float4*)(W2 + (size_t)(k0 + k) * VOCAB + n0 + tx * 4);
            tile[k][tx * 4 + 0] = v.x; tile[k][tx * 4 + 1] = v.y;
            tile[k][tx * 4 + 2] = v.z; tile[k][tx * 4 + 3] = v.w;
        }
        __syncthreads();
        int kx = t & 15, ny = t >> 4;
#pragma unroll
        for (int p = 0; p < 4; ++p) {
            int n = ny + p * 16;
            int k = kx * 4;
            union { unsigned short u[4]; uint2 v; } o;
            o.u[0] = f2bf(tile[k + 0][n]); o.u[1] = f2bf(tile[k + 1][n]);
            o.u[2] = f2bf(tile[k + 2][n]); o.u[3] = f2bf(tile[k + 3][n]);
            *(uint2*)(W2t + (size_t)(n0 + n) * EMBED + k0 + k) = o.v;
        }
    } else {
        int r = bid - 8000;
        int s = r >> 3, b = r & 7;
        int t0 = (s >= 3) ? toks[(s - 3) * BATCH + b] : 0;
        int t1 = (s >= 2) ? toks[(s - 2) * BATCH + b] : 0;
        int t2 = (s >= 1) ? toks[(s - 1) * BATCH + b] : 0;
        int e = t * 4;
        float4 vb = *(const float4*)(b1 + e);
        float4 v0 = *(const float4*)(W1 + ((size_t)0 * VOCAB + t0) * EMBED + e);
        float4 v1 = *(const float4*)(W1 + ((size_t)1 * VOCAB + t1) * EMBED + e);
        float4 v2 = *(const float4*)(W1 + ((size_t)2 * VOCAB + t2) * EMBED + e);
        float x0 = fmaxf(vb.x + v0.x + v1.x + v2.x, 0.0f);
        float x1 = fmaxf(vb.y + v0.y + v1.y + v2.y, 0.0f);
        float x2 = fmaxf(vb.z + v0.z + v1.z + v2.z, 0.0f);
        float x3 = fmaxf(vb.w + v0.w + v1.w + v2.w, 0.0f);
        union { unsigned short u[4]; uint2 v; } o;
        o.u[0] = f2bf(x0); o.u[1] = f2bf(x1); o.u[2] = f2bf(x2); o.u[3] = f2bf(x3);
        *(uint2*)(h + (size_t)r * EMBED + e) = o.v;
    }
}

// ---------------- persistent 256x256 8-phase bf16 MFMA GEMM: 2 m-tiles per block ----------------
// Round-3 structure (mg-inner XCD map, vmcnt-counted boundary) + NEW: full-line NT epilogue.
// Epilogue: acc -> LDS (dead buf1.A region, 32 KB = 32 rows x 1 KB) -> each wave stores
// one full 1 KB row segment per instr (64 lanes x float4) with nontemporal hint:
// full 128 B lines only => no RMW amplification; out stream bypasses cache => B stays in L3.
__global__ __launch_bounds__(512, 2) void gemm8_k(const unsigned short* __restrict__ A,
                                                  const unsigned short* __restrict__ B,
                                                  const float* __restrict__ b2,
                                                  float* __restrict__ out) {
    extern __shared__ char lds[];
    char* Al = lds;
    char* Bl = lds + 65536;

    // bijective XCD swizzle for 500 blocks (m204): q=62, r=4
    int wg = blockIdx.x;
    int xcd = wg & 7, idx = wg >> 3;
    int wgid = (xcd < 4 ? xcd * 63 : 4 * 63 + (xcd - 4) * 62) + idx;
    int mg = wgid & 3;            // m fast: same-stripe blocks adjacent (round-3 mapping)
    int n0 = (wgid >> 2) * BN;
    int m0 = mg * 512;

    int tid = threadIdx.x;
    int w = tid >> 6, lane = tid & 63;
    int wm = w >> 2, wn = w & 3;
    int ksw = ((lane & 7) ^ ((lane >> 3) & 7)) * 8;

    f32x4 acc[8][4] = {};
    short8 af[2][2], bfr[4][2];

    auto stage = [&](const unsigned short* __restrict__ g, int grow0, char* ldsbase, int t) {
#pragma unroll
        for (int j = 0; j < 2; ++j) {
            int c = j * 8 + w;
            int row = c * 8 + (lane >> 3);
            const unsigned short* src = g + (size_t)(grow0 + row) * EMBED + t * BK + ksw;
            GLOAD_LDS16(src, ldsbase + c * 1024);
        }
    };
    auto stA = [&](int buf, int hh, int t, int mbase) { stage(A, mbase + hh * 128, Al + buf * 32768 + hh * 16384, t); };
    auto stB = [&](int buf, int hh, int t) { stage(B, n0 + hh * 128, Bl + buf * 32768 + hh * 16384, t); };

    auto ldA = [&](int buf, int qq) {
#pragma unroll
        for (int i = 0; i < 2; ++i)
#pragma unroll
            for (int kk = 0; kk < 2; ++kk) {
                int row = wm * 128 + (qq * 2 + i) * 16 + (lane & 15);
                int cb = ((lane >> 4) * 16 + kk * 64) ^ ((lane & 7) << 4);
                af[i][kk] = *(const short8*)(Al + buf * 32768 + row * 128 + cb);
            }
    };
    auto ldB = [&](int buf) {
#pragma unroll
        for (int n = 0; n < 4; ++n)
#pragma unroll
            for (int kk = 0; kk < 2; ++kk) {
                int row = wn * 64 + n * 16 + (lane & 15);
                int cb = ((lane >> 4) * 16 + kk * 64) ^ ((lane & 7) << 4);
                bfr[n][kk] = *(const short8*)(Bl + buf * 32768 + row * 128 + cb);
            }
    };

#define MFMA_Q(q)                                                                             \
    __builtin_amdgcn_s_setprio(1);                                                            \
    _Pragma("unroll") for (int i = 0; i < 2; ++i)                                             \
        _Pragma("unroll") for (int n = 0; n < 4; ++n)                                         \
            _Pragma("unroll") for (int kk = 0; kk < 2; ++kk)                                  \
                acc[(q)*2 + i][n] = __builtin_amdgcn_mfma_f32_16x16x32_bf16(                  \
                    af[i][kk], bfr[n][kk], acc[(q)*2 + i][n], 0, 0, 0);                       \
    __builtin_amdgcn_s_setprio(0);

#define PH(ldbuf, q, DO_LDB, STAGE_STMT, WAITV)                                               \
    ldA(ldbuf, q);                                                                            \
    if (DO_LDB) ldB(ldbuf);                                                                   \
    STAGE_STMT;                                                                               \
    if (DO_LDB) asm volatile("s_waitcnt lgkmcnt(8)");                                         \
    if (WAITV) asm volatile("s_waitcnt vmcnt(4)");                                            \
    __builtin_amdgcn_s_barrier();                                                             \
    asm volatile("s_waitcnt lgkmcnt(0)");                                                     \
    MFMA_Q(q);                                                                                \
    __builtin_amdgcn_s_barrier();

    auto kloop = [&](int mcur) {
        for (int it = 0; it < NT / 2; ++it) {
            int t1 = (it * 2 + 1) & (NT - 1);
            int t2 = (it * 2 + 2) & (NT - 1);
            int t3 = (it * 2 + 3) & (NT - 1);
            PH(0, 0, true,  stA(1, 0, t1, mcur), false)
            PH(0, 1, false, stA(1, 1, t1, mcur), false)
            PH(0, 2, false, stB(0, 0, t2),       false)
            PH(0, 3, false, stB(0, 1, t2),       true)
            PH(1, 0, true,  stA(0, 0, t2, mcur), false)
            PH(1, 1, false, stA(0, 1, t2, mcur), false)
            PH(1, 2, false, stB(1, 0, t3),       false)
            PH(1, 3, false, stB(1, 1, t3),       true)
        }
    };

    // ---- full-line NT epilogue via LDS transpose (uses dead buf1.A region, 32 KB) ----
    // Pass p (0..7): rows mbase+p*32 .. +31. Dump: waves wm==p>>2 write acc (mf pair) into
    // T[row_local][col]; readback: wave w stores rows w*4+rr as 1 KB contiguous NT float4.
    int colq = lane & 15;
    int rowq4 = (lane >> 4) * 4;
    auto epi = [&](int mbase) {
        char* T = Al + 32768;
        float bias[4];
#pragma unroll
        for (int nf = 0; nf < 4; ++nf) bias[nf] = b2[n0 + wn * 64 + nf * 16 + colq];
#pragma unroll
        for (int p = 0; p < 8; ++p) {
            __builtin_amdgcn_s_barrier();   // prior pass readback done before overwrite
            if (wm == (p >> 2)) {
#pragma unroll
                for (int mi = 0; mi < 2; ++mi) {
                    int mf = (p & 3) * 2 + mi;
                    int rl = mi * 16 + rowq4;
#pragma unroll
                    for (int nf = 0; nf < 4; ++nf) {
                        int c = wn * 64 + nf * 16 + colq;
#pragma unroll
                        for (int q = 0; q < 4; ++q)
                            *(float*)(T + (rl + q) * 1024 + c * 4) = acc[mf][nf][q] + bias[nf];
                    }
                }
            }
            __builtin_amdgcn_s_barrier();
#pragma unroll
            for (int rr = 0; rr < 4; ++rr) {
                int rl = w * 4 + rr;
                f32x4 v = *(const f32x4*)(T + rl * 1024 + lane * 16);
                int grow = mbase + p * 32 + rl;
                __builtin_nontemporal_store(v, (f32x4*)(out + (size_t)grow * VOCAB + n0 + lane * 4));
            }
        }
    };

    // ---- prologue (m-tile 0) ----
    stA(0, 0, 0, m0); stA(0, 1, 0, m0); stB(0, 0, 0); stB(0, 1, 0);
    stB(1, 0, 1); stB(1, 1, 1);
    asm volatile("s_waitcnt vmcnt(4)");
    __builtin_amdgcn_s_barrier();

    kloop(m0);

    // ---- boundary: wrap prefetch left buf0.B=B(t0), buf1.B=B(t1). Prestage A(t0,m1)
    // into buf0.A BEFORE the epilogue stores; epi's bias loads (younger vmem) force
    // in-order retirement of the prestage; vmcnt(32) + barrier make it explicit.
    int m1 = m0 + 256;
    stA(0, 0, 0, m1); stA(0, 1, 0, m1);
    epi(m0);
    asm volatile("s_waitcnt vmcnt(32)" ::: "memory");
    __builtin_amdgcn_s_barrier();

#pragma unroll
    for (int mf = 0; mf < 8; ++mf)
#pragma unroll
        for (int nf = 0; nf < 4; ++nf)
            acc[mf][nf] = f32x4{0.f, 0.f, 0.f, 0.f};

    kloop(m1);
    epi(m1);
#undef PH
#undef MFMA_Q
}

// ---------------- fallback 128^2 2-phase GEMM (if 128 KiB dyn LDS unavailable) ----------------
__global__ __launch_bounds__(256) void gemm_k(const unsigned short* __restrict__ h,
                                              const unsigned short* __restrict__ W2t,
                                              const float* __restrict__ b2,
                                              float* __restrict__ out) {
    __shared__ unsigned short Alds[128 * 64];
    __shared__ unsigned short Blds[128 * 64];
    int m0 = blockIdx.x * 128;
    int n0 = blockIdx.y * 128;
    int tid = threadIdx.x;
    int wave = tid >> 6, lane = tid & 63;
    int wr = (wave >> 1) * 64;
    int wc = (wave & 1) * 64;
    int lrow = lane & 15;
    int khalf = (lane >> 4) * 8;
    f32x4 acc[4][4] = {};
    for (int kt = 0; kt < EMBED; kt += 64) {
#pragma unroll
        for (int i = 0; i < 4; ++i) {
            int base = (wave * 4 + i) * 1024;
            int lin = base + lane * 16;
            int row = lin >> 7;
            int colu = (lin & 127) >> 1;
            GLOAD_LDS16(h + (size_t)(m0 + row) * EMBED + kt + colu, (char*)Alds + base);
            GLOAD_LDS16(W2t + (size_t)(n0 + row) * EMBED + kt + colu, (char*)Blds + base);
        }
        __syncthreads();
#pragma unroll
        for (int kc = 0; kc < 2; ++kc) {
            short8 af[4], bf[4];
#pragma unroll
            for (int m = 0; m < 4; ++m)
                af[m] = *(const short8*)(Alds + (wr + m * 16 + lrow) * 64 + kc * 32 + khalf);
#pragma unroll
            for (int n = 0; n < 4; ++n)
                bf[n] = *(const short8*)(Blds + (wc + n * 16 + lrow) * 64 + kc * 32 + khalf);
#pragma unroll
            for (int m = 0; m < 4; ++m)
#pragma unroll
                for (int n = 0; n < 4; ++n)
                    acc[m][n] = __builtin_amdgcn_mfma_f32_16x16x32_bf16(af[m], bf[n], acc[m][n], 0, 0, 0);
        }
        __syncthreads();
    }
    int colq = lane & 15;
    int rowq = (lane >> 4) * 4;
#pragma unroll
    for (int m = 0; m < 4; ++m)
#pragma unroll
        for (int n = 0; n < 4; ++n) {
            int col = n0 + wc + n * 16 + colq;
            float bias = b2[col];
#pragma unroll
            for (int q = 0; q < 4; ++q)
                out[(size_t)(m0 + wr + m * 16 + rowq + q) * VOCAB + col] = acc[m][n][q] + bias;
        }
}

// ---------------- fallback (ws too small): correct fp32 path ----------------
__global__ __launch_bounds__(256) void naive_k(const int* __restrict__ toks,
                                               const float* __restrict__ W1,
                                               const float* __restrict__ b1,
                                               const float* __restrict__ W2,
                                               const float* __restrict__ b2,
                                               float* __restrict__ out) {
    __shared__ float hs[8][1024];
    int r0 = blockIdx.x * 8;
    int e = threadIdx.x * 4;
    for (int rr = 0; rr < 8; ++rr) {
        int r = r0 + rr, s = r >> 3, b = r & 7;
        int t0 = (s >= 3) ? toks[(s - 3) * BATCH + b] : 0;
        int t1 = (s >= 2) ? toks[(s - 2) * BATCH + b] : 0;
        int t2 = (s >= 1) ? toks[(s - 1) * BATCH + b] : 0;
        float4 vb = *(const float4*)(b1 + e);
        float4 v0 = *(const float4*)(W1 + ((size_t)t0) * EMBED + e);
        float4 v1 = *(const float4*)(W1 + ((size_t)VOCAB + t1) * EMBED + e);
        float4 v2 = *(const float4*)(W1 + ((size_t)2 * VOCAB + t2) * EMBED + e);
        hs[rr][e + 0] = fmaxf(vb.x + v0.x + v1.x + v2.x, 0.0f);
        hs[rr][e + 1] = fmaxf(vb.y + v0.y + v1.y + v2.y, 0.0f);
        hs[rr][e + 2] = fmaxf(vb.z + v0.z + v1.z + v2.z, 0.0f);
        hs[rr][e + 3] = fmaxf(vb.w + v0.w + v1.w + v2.w, 0.0f);
    }
    __syncthreads();
    for (int v = threadIdx.x; v < VOCAB; v += 256) {
        float acc[8];
#pragma unroll
        for (int i = 0; i < 8; ++i) acc[i] = b2[v];
        for (int ee = 0; ee < EMBED; ++ee) {
            float wv = W2[(size_t)ee * VOCAB + v];
#pragma unroll
            for (int i = 0; i < 8; ++i) acc[i] += hs[i][ee] * wv;
        }
#pragma unroll
        for (int i = 0; i < 8; ++i) out[(size_t)(r0 + i) * VOCAB + v] = acc[i];
    }
}

extern "C" void kernel_launch(void* const* d_in, const int* in_sizes, int n_in,
                              void* d_out, int out_size, void* d_ws, size_t ws_size,
                              hipStream_t stream) {
    const int* toks = (const int*)d_in[0];
    const float* W1 = (const float*)d_in[1];
    const float* b1 = (const float*)d_in[2];
    const float* W2 = (const float*)d_in[3];
    const float* b2 = (const float*)d_in[4];
    float* out = (float*)d_out;

    const size_t h_bytes = (size_t)ROWS * EMBED * 2;
    const size_t w2t_bytes = (size_t)VOCAB * EMBED * 2;
    if (ws_size >= h_bytes + w2t_bytes) {
        unsigned short* h = (unsigned short*)d_ws;
        unsigned short* W2t = (unsigned short*)((char*)d_ws + h_bytes);
        prep_k<<<8000 + ROWS, 256, 0, stream>>>(toks, W1, b1, W2, h, W2t);
        hipError_t e = hipFuncSetAttribute(reinterpret_cast<const void*>(gemm8_k),
                                           hipFuncAttributeMaxDynamicSharedMemorySize, 131072);
        if (e == hipSuccess) {
            gemm8_k<<<(ROWS / 512) * (VOCAB / BN), 512, 131072, stream>>>(h, W2t, b2, out);
        } else {
            gemm_k<<<dim3(ROWS / 128, VOCAB / 128), 256, 0, stream>>>(h, W2t, b2, out);
        }
    } else {
        naive_k<<<ROWS / 8, 256, 0, stream>>>(toks, W1, b1, W2, b2, out);
    }
}